// Round 4
// baseline (176.702 us; speedup 1.0000x reference)
//
#include <hip/hip_runtime.h>

#define NPATH 60
#define KDIM  204
#define KPAD  224      // 7 k-chunks of 32, zero padded
#define NIJ   324
#define NTIL  21       // 21 n-tiles of 16 (324 -> 336)
#define HID   64

typedef short bf16x8 __attribute__((ext_vector_type(8)));
typedef float f32x4  __attribute__((ext_vector_type(4)));

__device__ inline unsigned short f2bf(float f) {
    unsigned int u = __builtin_bit_cast(unsigned int, f);
    u += 0x7fffu + ((u >> 16) & 1u);     // RNE
    return (unsigned short)(u >> 16);
}
__device__ inline float bf2f(unsigned short h) {
    unsigned int u = ((unsigned int)h) << 16;
    return __builtin_bit_cast(float, u);
}

// Phase-overlapped LDS: Blds/Hlds/w1/w2 all dead before Clds is written.
union SmemU {
    struct {
        unsigned short Blds[64][72];   // radial basis, bf16
        unsigned short Hlds[64][72];   // hidden activations, bf16
        unsigned short w1[4096];       // W1 swizzled to B-fragment order
        unsigned short w2[4096];       // W2 swizzled (n>=60 zero)
    } p1;                              // 34,816 B
    unsigned short Clds[64][232];      // coeff bf16, k-padded to 224 (+8 pad)
};

__global__ __launch_bounds__(256) void fused_kernel(
    const float* __restrict__ r,  const float* __restrict__ W1,
    const float* __restrict__ b1, const float* __restrict__ W2,
    const float* __restrict__ b2, const float* __restrict__ cg,
    const float* __restrict__ rf, const float* __restrict__ ylm,
    float* __restrict__ out)
{
    __shared__ SmemU sm;
    __shared__ unsigned short Rl[64][61];   // R, bf16
    __shared__ float Yl[64][9];
    __shared__ float radl[64];
    __shared__ unsigned char ptab[KDIM];
    __shared__ unsigned char ytab[KDIM];

    const int tid  = threadIdx.x;
    const int wv   = tid >> 6;
    const int lane = tid & 63;
    const int quad = lane >> 4;
    const int l16  = lane & 15;
    const int z0   = blockIdx.x * 64;

    // ---- Phase A: radius + spherical harmonics ----
    if (tid < 64) {
        int z = z0 + tid;
        float x = r[z * 3 + 0], y = r[z * 3 + 1], zc = r[z * 3 + 2];
        float rad = sqrtf(x * x + y * y + zc * zc);
        float inv = 1.0f / (rad + 1e-12f);
        float nx = x * inv, ny = y * inv, nz = zc * inv;
        radl[tid] = rad;
        const float c0 = 0.28209479177387814f, c1 = 0.4886025119029199f;
        const float c2a = 1.0925484305920792f, c2b = 0.31539156525252005f, c2c = 0.5462742152960396f;
        Yl[tid][0] = c0;
        Yl[tid][1] = c1 * ny;
        Yl[tid][2] = c1 * nz;
        Yl[tid][3] = c1 * nx;
        Yl[tid][4] = c2a * nx * ny;
        Yl[tid][5] = c2a * ny * nz;
        Yl[tid][6] = c2b * (3.0f * nz * nz - 1.0f);
        Yl[tid][7] = c2a * nx * nz;
        Yl[tid][8] = c2c * (nx * nx - ny * ny);
    }
    // gather tables: all 204 rows (grid-stride over block threads)
    for (int k = tid; k < KDIM; k += 256) {
        int p = 0, yy = 0;
        for (int q = 0; q < NPATH; q++) if (rf[k * NPATH + q] != 0.0f) p = q;
        for (int q = 0; q < 9; q++)     if (ylm[k * 9 + q]   != 0.0f) yy = q;
        ptab[k] = (unsigned char)p;
        ytab[k] = (unsigned char)yy;
    }
    __syncthreads();

    // ---- Phase A2: radial basis (bf16) + W1/W2 LDS swizzle ----
    {
        int zz = tid >> 2, grp = tid & 3;
        float rad = radl[zz];
        unsigned int* dst = (unsigned int*)&sm.p1.Blds[zz][grp * 16];
        const float step = 3.5f / 63.0f;
        #pragma unroll
        for (int ii = 0; ii < 8; ii++) {
            int i0 = grp * 16 + ii * 2;
            float d0 = rad - (float)i0 * step;
            float d1 = rad - (float)(i0 + 1) * step;
            unsigned int u0 = f2bf(expf(-4.0f * d0 * d0));
            unsigned int u1 = f2bf(expf(-4.0f * d1 * d1));
            dst[ii] = u0 | (u1 << 16);
        }
    }
    for (int i = tid; i < 4096; i += 256) {
        int e = i & 7, ln = (i >> 3) & 63, nt = (i >> 9) & 3, kc = i >> 11;
        int k = kc * 32 + (ln >> 4) * 8 + e;
        int n = nt * 16 + (ln & 15);
        sm.p1.w1[i] = f2bf(W1[k * HID + n]);
        sm.p1.w2[i] = f2bf(n < NPATH ? W2[k * NPATH + n] : 0.0f);
    }
    __syncthreads();

    // ---- Phase B: H = relu(B @ W1 + b1); wave wv owns z rows [16wv,16wv+16) ----
    {
        bf16x8 a0 = *(const bf16x8*)&sm.p1.Blds[wv * 16 + l16][0 + quad * 8];
        bf16x8 a1 = *(const bf16x8*)&sm.p1.Blds[wv * 16 + l16][32 + quad * 8];
        #pragma unroll
        for (int nt = 0; nt < 4; nt++) {
            bf16x8 bb0 = *(const bf16x8*)&sm.p1.w1[((0 * 4 + nt) * 64 + lane) * 8];
            bf16x8 bb1 = *(const bf16x8*)&sm.p1.w1[((1 * 4 + nt) * 64 + lane) * 8];
            f32x4 acc = {0.f, 0.f, 0.f, 0.f};
            acc = __builtin_amdgcn_mfma_f32_16x16x32_bf16(a0, bb0, acc, 0, 0, 0);
            acc = __builtin_amdgcn_mfma_f32_16x16x32_bf16(a1, bb1, acc, 0, 0, 0);
            int h = nt * 16 + l16;
            float bias = b1[h];
            #pragma unroll
            for (int rr = 0; rr < 4; rr++) {
                float v = acc[rr] + bias;
                v = v > 0.0f ? v : 0.0f;
                sm.p1.Hlds[wv * 16 + quad * 4 + rr][h] = f2bf(v);
            }
        }
    }
    __syncthreads();

    // ---- Phase C: R = H @ W2 + b2 -> bf16 Rl ----
    {
        bf16x8 a0 = *(const bf16x8*)&sm.p1.Hlds[wv * 16 + l16][0 + quad * 8];
        bf16x8 a1 = *(const bf16x8*)&sm.p1.Hlds[wv * 16 + l16][32 + quad * 8];
        #pragma unroll
        for (int nt = 0; nt < 4; nt++) {
            bf16x8 bb0 = *(const bf16x8*)&sm.p1.w2[((0 * 4 + nt) * 64 + lane) * 8];
            bf16x8 bb1 = *(const bf16x8*)&sm.p1.w2[((1 * 4 + nt) * 64 + lane) * 8];
            f32x4 acc = {0.f, 0.f, 0.f, 0.f};
            acc = __builtin_amdgcn_mfma_f32_16x16x32_bf16(a0, bb0, acc, 0, 0, 0);
            acc = __builtin_amdgcn_mfma_f32_16x16x32_bf16(a1, bb1, acc, 0, 0, 0);
            int p = nt * 16 + l16;
            if (p < NPATH) {
                float bias = b2[p];
                #pragma unroll
                for (int rr = 0; rr < 4; rr++)
                    Rl[wv * 16 + quad * 4 + rr][p] = f2bf(acc[rr] + bias);
            }
        }
    }
    __syncthreads();

    // ---- Phase D: coeff[z][k] = R[z][p(k)] * Y[z][y(k)] -> bf16, k-pad to 224 ----
    for (int idx = tid; idx < 64 * (KPAD / 2); idx += 256) {
        int z = idx / (KPAD / 2);
        int k = (idx % (KPAD / 2)) * 2;
        unsigned int u = 0;
        if (k < KDIM) {   // pairs never straddle: KDIM even
            float cA = bf2f(Rl[z][ptab[k]])     * Yl[z][ytab[k]];
            float cB = bf2f(Rl[z][ptab[k + 1]]) * Yl[z][ytab[k + 1]];
            u = (unsigned int)f2bf(cA) | ((unsigned int)f2bf(cB) << 16);
        }
        *(unsigned int*)&sm.Clds[z][k] = u;
    }
    __syncthreads();

    // ---- Phase E: out = coeff @ cg; cg streamed from global fp32 -> bf16 frags ----
    {
        const int ntb = wv * 5 + (wv > 0 ? 1 : 0);   // w0: nt 0-5, w1: 6-10, w2: 11-15, w3: 16-20
        const int cnt = (wv == 0) ? 6 : 5;

        f32x4 acc[6][4];
        #pragma unroll
        for (int i = 0; i < 6; i++)
            #pragma unroll
            for (int zt = 0; zt < 4; zt++)
                acc[i][zt] = (f32x4){0.f, 0.f, 0.f, 0.f};

        #pragma unroll
        for (int kc = 0; kc < 7; kc++) {
            bf16x8 az[4];
            #pragma unroll
            for (int zt = 0; zt < 4; zt++)
                az[zt] = *(const bf16x8*)&sm.Clds[zt * 16 + l16][kc * 32 + quad * 8];

            const int kb = kc * 32 + quad * 8;
            #pragma unroll
            for (int i = 0; i < 6; i++) {
                if (i < cnt) {
                    int col = (ntb + i) * 16 + l16;
                    union { bf16x8 v; unsigned int u[4]; } bu;
                    #pragma unroll
                    for (int e = 0; e < 4; e++) {
                        int k0 = kb + 2 * e;            // k0 even; k0 < KDIM implies k0+1 < KDIM
                        bool ok = (col < NIJ) && (k0 < KDIM);
                        float v0 = ok ? cg[k0 * NIJ + col]       : 0.0f;
                        float v1 = ok ? cg[(k0 + 1) * NIJ + col] : 0.0f;
                        bu.u[e] = (unsigned int)f2bf(v0) | ((unsigned int)f2bf(v1) << 16);
                    }
                    #pragma unroll
                    for (int zt = 0; zt < 4; zt++)
                        acc[i][zt] = __builtin_amdgcn_mfma_f32_16x16x32_bf16(az[zt], bu.v, acc[i][zt], 0, 0, 0);
                }
            }
        }

        #pragma unroll
        for (int i = 0; i < 6; i++) {
            if (i < cnt) {
                int col = (ntb + i) * 16 + l16;
                if (col < NIJ) {
                    #pragma unroll
                    for (int zt = 0; zt < 4; zt++) {
                        #pragma unroll
                        for (int rr = 0; rr < 4; rr++) {
                            int z = z0 + zt * 16 + quad * 4 + rr;
                            out[z * NIJ + col] = acc[i][zt][rr];
                        }
                    }
                }
            }
        }
    }
}

extern "C" void kernel_launch(void* const* d_in, const int* in_sizes, int n_in,
                              void* d_out, int out_size, void* d_ws, size_t ws_size,
                              hipStream_t stream) {
    const float* r   = (const float*)d_in[0];
    const float* W1  = (const float*)d_in[1];
    const float* b1  = (const float*)d_in[2];
    const float* W2  = (const float*)d_in[3];
    const float* b2  = (const float*)d_in[4];
    const float* cg  = (const float*)d_in[5];
    const float* rf  = (const float*)d_in[6];
    const float* ylm = (const float*)d_in[7];
    float* out = (float*)d_out;

    const int Z = in_sizes[0] / 3;

    fused_kernel<<<Z / 64, 256, 0, stream>>>(r, W1, b1, W2, b2, cg, rf, ylm, out);
}

// Round 5
// 138.903 us; speedup vs baseline: 1.2721x; 1.2721x over previous
//
#include <hip/hip_runtime.h>

#define NPATH 60
#define KDIM  204
#define KPAD  224      // 7 k-chunks of 32, zero padded
#define NIJ   324
#define NTIL  21       // 21 n-tiles of 16 (324 -> 336)
#define HID   64

typedef short bf16x8 __attribute__((ext_vector_type(8)));
typedef float f32x4  __attribute__((ext_vector_type(4)));

// One-time prepped operands in bf16 MFMA B-fragment order (module globals:
// graph-safe, rewritten by prep_kernel every call).
__device__ __align__(16) unsigned short g_w1s[4096];    // 2kc x 4nt x 64lane x 8
__device__ __align__(16) unsigned short g_w2s[4096];
__device__ __align__(16) unsigned short g_cgs[75264];   // 7kc x 21nt x 64lane x 8
__device__ unsigned char g_ptab[KDIM];
__device__ unsigned char g_ytab[KDIM];

__device__ inline unsigned short f2bf(float f) {
    unsigned int u = __builtin_bit_cast(unsigned int, f);
    u += 0x7fffu + ((u >> 16) & 1u);     // RNE
    return (unsigned short)(u >> 16);
}
__device__ inline float bf2f(unsigned short h) {
    unsigned int u = ((unsigned int)h) << 16;
    return __builtin_bit_cast(float, u);
}

__global__ void prep_kernel(const float* __restrict__ W1, const float* __restrict__ W2,
                            const float* __restrict__ cg, const float* __restrict__ rf,
                            const float* __restrict__ ylm)
{
    int idx = blockIdx.x * 256 + threadIdx.x;
    if (idx < 4096) {                                       // W1 -> fragment order
        int e = idx & 7, ln = (idx >> 3) & 63, nt = (idx >> 9) & 3, kc = idx >> 11;
        int k = kc * 32 + (ln >> 4) * 8 + e;
        int n = nt * 16 + (ln & 15);
        g_w1s[idx] = f2bf(W1[k * HID + n]);
    } else if (idx < 8192) {                                // W2 (n>=60 zero)
        int j = idx - 4096;
        int e = j & 7, ln = (j >> 3) & 63, nt = (j >> 9) & 3, kc = j >> 11;
        int k = kc * 32 + (ln >> 4) * 8 + e;
        int n = nt * 16 + (ln & 15);
        g_w2s[j] = f2bf(n < NPATH ? W2[k * NPATH + n] : 0.0f);
    } else if (idx < 8192 + 75264) {                        // cg (k>=204 / n>=324 zero)
        int j = idx - 8192;
        int e = j & 7, ln = (j >> 3) & 63;
        int nt = (j >> 9) % NTIL;
        int kc = j / (512 * NTIL);
        int k = kc * 32 + (ln >> 4) * 8 + e;
        int n = nt * 16 + (ln & 15);
        g_cgs[j] = f2bf((k < KDIM && n < NIJ) ? cg[k * NIJ + n] : 0.0f);
    } else if (idx < 8192 + 75264 + KDIM) {                 // gather tables
        int k = idx - (8192 + 75264);
        int p = 0, yy = 0;
        for (int q = 0; q < NPATH; q++) if (rf[k * NPATH + q] != 0.0f) p = q;
        for (int q = 0; q < 9; q++)     if (ylm[k * 9 + q]   != 0.0f) yy = q;
        g_ptab[k] = (unsigned char)p;
        g_ytab[k] = (unsigned char)yy;
    }
}

// Phase-overlapped LDS: Blds/Hlds dead before Clds; Clds dead before stage.
union SmemU {
    struct {
        unsigned short Blds[64][72];   // radial basis, bf16
        unsigned short Hlds[64][72];   // hidden activations, bf16
    } p1;                              // 18,432 B
    unsigned short Clds[64][228];      // coeff bf16, k-padded to 224  (29,184 B)
    float stage[16][340];              // epilogue transpose            (21,760 B)
};

__global__ __launch_bounds__(256) void fused_kernel(
    const float* __restrict__ r, const float* __restrict__ b1,
    const float* __restrict__ b2, float* __restrict__ out)
{
    __shared__ SmemU sm;
    __shared__ unsigned short Rl[64][61];   // R, bf16
    __shared__ float Yl[64][9];
    __shared__ float radl[64];
    __shared__ unsigned char ptabL[KDIM];
    __shared__ unsigned char ytabL[KDIM];

    const int tid  = threadIdx.x;
    const int wv   = tid >> 6;
    const int lane = tid & 63;
    const int quad = lane >> 4;
    const int l16  = lane & 15;
    const int z0   = blockIdx.x * 64;

    // ---- Phase A: radius + spherical harmonics; copy gather tables to LDS ----
    if (tid < 64) {
        int z = z0 + tid;
        float x = r[z * 3 + 0], y = r[z * 3 + 1], zc = r[z * 3 + 2];
        float rad = sqrtf(x * x + y * y + zc * zc);
        float inv = 1.0f / (rad + 1e-12f);
        float nx = x * inv, ny = y * inv, nz = zc * inv;
        radl[tid] = rad;
        const float c0 = 0.28209479177387814f, c1 = 0.4886025119029199f;
        const float c2a = 1.0925484305920792f, c2b = 0.31539156525252005f, c2c = 0.5462742152960396f;
        Yl[tid][0] = c0;
        Yl[tid][1] = c1 * ny;
        Yl[tid][2] = c1 * nz;
        Yl[tid][3] = c1 * nx;
        Yl[tid][4] = c2a * nx * ny;
        Yl[tid][5] = c2a * ny * nz;
        Yl[tid][6] = c2b * (3.0f * nz * nz - 1.0f);
        Yl[tid][7] = c2a * nx * nz;
        Yl[tid][8] = c2c * (nx * nx - ny * ny);
    }
    for (int k = tid; k < KDIM; k += 256) {
        ptabL[k] = g_ptab[k];
        ytabL[k] = g_ytab[k];
    }
    __syncthreads();

    // ---- Phase A2: Gaussian radial basis -> bf16 Blds ----
    {
        int zz = tid >> 2, grp = tid & 3;
        float rad = radl[zz];
        unsigned int* dst = (unsigned int*)&sm.p1.Blds[zz][grp * 16];
        const float step = 3.5f / 63.0f;
        #pragma unroll
        for (int ii = 0; ii < 8; ii++) {
            int i0 = grp * 16 + ii * 2;
            float d0 = rad - (float)i0 * step;
            float d1 = rad - (float)(i0 + 1) * step;
            unsigned int u0 = f2bf(expf(-4.0f * d0 * d0));
            unsigned int u1 = f2bf(expf(-4.0f * d1 * d1));
            dst[ii] = u0 | (u1 << 16);
        }
    }
    __syncthreads();

    // ---- Phase B: H = relu(B @ W1 + b1); W1 fragments straight from global ----
    {
        bf16x8 a0 = *(const bf16x8*)&sm.p1.Blds[wv * 16 + l16][0 + quad * 8];
        bf16x8 a1 = *(const bf16x8*)&sm.p1.Blds[wv * 16 + l16][32 + quad * 8];
        #pragma unroll
        for (int nt = 0; nt < 4; nt++) {
            bf16x8 bb0 = *(const bf16x8*)&g_w1s[((0 * 4 + nt) * 64 + lane) * 8];
            bf16x8 bb1 = *(const bf16x8*)&g_w1s[((1 * 4 + nt) * 64 + lane) * 8];
            f32x4 acc = {0.f, 0.f, 0.f, 0.f};
            acc = __builtin_amdgcn_mfma_f32_16x16x32_bf16(a0, bb0, acc, 0, 0, 0);
            acc = __builtin_amdgcn_mfma_f32_16x16x32_bf16(a1, bb1, acc, 0, 0, 0);
            int h = nt * 16 + l16;
            float bias = b1[h];
            #pragma unroll
            for (int rr = 0; rr < 4; rr++) {
                float v = acc[rr] + bias;
                v = v > 0.0f ? v : 0.0f;
                sm.p1.Hlds[wv * 16 + quad * 4 + rr][h] = f2bf(v);
            }
        }
    }
    __syncthreads();

    // ---- Phase C: R = H @ W2 + b2 -> bf16 Rl ----
    {
        bf16x8 a0 = *(const bf16x8*)&sm.p1.Hlds[wv * 16 + l16][0 + quad * 8];
        bf16x8 a1 = *(const bf16x8*)&sm.p1.Hlds[wv * 16 + l16][32 + quad * 8];
        #pragma unroll
        for (int nt = 0; nt < 4; nt++) {
            bf16x8 bb0 = *(const bf16x8*)&g_w2s[((0 * 4 + nt) * 64 + lane) * 8];
            bf16x8 bb1 = *(const bf16x8*)&g_w2s[((1 * 4 + nt) * 64 + lane) * 8];
            f32x4 acc = {0.f, 0.f, 0.f, 0.f};
            acc = __builtin_amdgcn_mfma_f32_16x16x32_bf16(a0, bb0, acc, 0, 0, 0);
            acc = __builtin_amdgcn_mfma_f32_16x16x32_bf16(a1, bb1, acc, 0, 0, 0);
            int p = nt * 16 + l16;
            if (p < NPATH) {
                float bias = b2[p];
                #pragma unroll
                for (int rr = 0; rr < 4; rr++)
                    Rl[wv * 16 + quad * 4 + rr][p] = f2bf(acc[rr] + bias);
            }
        }
    }
    __syncthreads();

    // ---- Phase D: coeff[z][k] = R[z][p(k)] * Y[z][y(k)] -> bf16, k-pad to 224 ----
    for (int idx = tid; idx < 64 * (KPAD / 2); idx += 256) {
        int z = idx / (KPAD / 2);
        int k = (idx % (KPAD / 2)) * 2;
        unsigned int u = 0;
        if (k < KDIM) {   // KDIM even: pairs never straddle
            float cA = bf2f(Rl[z][ptabL[k]])     * Yl[z][ytabL[k]];
            float cB = bf2f(Rl[z][ptabL[k + 1]]) * Yl[z][ytabL[k + 1]];
            u = (unsigned int)f2bf(cA) | ((unsigned int)f2bf(cB) << 16);
        }
        *(unsigned int*)&sm.Clds[z][k] = u;
    }
    __syncthreads();

    // ---- Phase E: out = coeff @ cg; cg fragments are 16B global loads ----
    const int ntb = wv * 5 + (wv > 0 ? 1 : 0);   // w0: nt 0-5, w1: 6-10, w2: 11-15, w3: 16-20
    const int cnt = (wv == 0) ? 6 : 5;

    f32x4 acc[6][4];
    #pragma unroll
    for (int i = 0; i < 6; i++)
        #pragma unroll
        for (int zt = 0; zt < 4; zt++)
            acc[i][zt] = (f32x4){0.f, 0.f, 0.f, 0.f};

    #pragma unroll
    for (int kc = 0; kc < 7; kc++) {
        bf16x8 az[4];
        #pragma unroll
        for (int zt = 0; zt < 4; zt++)
            az[zt] = *(const bf16x8*)&sm.Clds[zt * 16 + l16][kc * 32 + quad * 8];

        bf16x8 bg[6];
        #pragma unroll
        for (int i = 0; i < 6; i++) {
            int nt = ntb + i; if (nt > NTIL - 1) nt = NTIL - 1;   // clamp keeps load in-bounds
            bg[i] = *(const bf16x8*)&g_cgs[((kc * NTIL + nt) * 64 + lane) * 8];
        }
        #pragma unroll
        for (int i = 0; i < 6; i++) {
            if (i < cnt) {
                #pragma unroll
                for (int zt = 0; zt < 4; zt++)
                    acc[i][zt] = __builtin_amdgcn_mfma_f32_16x16x32_bf16(az[zt], bg[i], acc[i][zt], 0, 0, 0);
            }
        }
    }

    // ---- Epilogue: LDS transpose -> float4 coalesced stores ----
    for (int zt = 0; zt < 4; zt++) {
        __syncthreads();                         // zt=0: Clds reads done; else: stage reuse
        #pragma unroll
        for (int i = 0; i < 6; i++) {
            if (i < cnt) {
                int col = (ntb + i) * 16 + l16;  // <= 335 < 340
                #pragma unroll
                for (int rr = 0; rr < 4; rr++)
                    sm.stage[quad * 4 + rr][col] = acc[i][zt][rr];
            }
        }
        __syncthreads();
        for (int j = tid; j < 16 * (NIJ / 4); j += 256) {
            int row = j / (NIJ / 4);
            int c4  = j % (NIJ / 4);
            f32x4 v = *(const f32x4*)&sm.stage[row][c4 * 4];
            *(f32x4*)&out[(z0 + zt * 16 + row) * NIJ + c4 * 4] = v;
        }
    }
}

extern "C" void kernel_launch(void* const* d_in, const int* in_sizes, int n_in,
                              void* d_out, int out_size, void* d_ws, size_t ws_size,
                              hipStream_t stream) {
    const float* r   = (const float*)d_in[0];
    const float* W1  = (const float*)d_in[1];
    const float* b1  = (const float*)d_in[2];
    const float* W2  = (const float*)d_in[3];
    const float* b2  = (const float*)d_in[4];
    const float* cg  = (const float*)d_in[5];
    const float* rf  = (const float*)d_in[6];
    const float* ylm = (const float*)d_in[7];
    float* out = (float*)d_out;

    const int Z = in_sizes[0] / 3;

    prep_kernel<<<327, 256, 0, stream>>>(W1, W2, cg, rf, ylm);
    fused_kernel<<<Z / 64, 256, 0, stream>>>(r, b1, b2, out);
}